// Round 8
// baseline (141.314 us; speedup 1.0000x reference)
//
#include <hip/hip_runtime.h>

typedef __attribute__((ext_vector_type(8))) short short8;
typedef __attribute__((ext_vector_type(4))) short short4v;
typedef __attribute__((ext_vector_type(4))) float floatx4;
typedef __attribute__((ext_vector_type(4))) unsigned uintx4;

#define D 128
#define NWAVES 4
#define GRID_MLP 512

__device__ __forceinline__ unsigned short f2bf(float f) {
  unsigned u = __float_as_uint(f);
  u += 0x7FFFu + ((u >> 16) & 1u);   // RNE
  return (unsigned short)(u >> 16);
}

// Packed f32x2 -> bf16x2 (RNE). gfx950 has v_cvt_pk_bf16_f32 (1 instr);
// fall back to the manual bit-trick if the builtin is unavailable.
__device__ __forceinline__ unsigned pkbf(float lo, float hi) {
#if __has_builtin(__builtin_amdgcn_cvt_pk_bf16_f32)
  auto v = __builtin_amdgcn_cvt_pk_bf16_f32(lo, hi);
  unsigned u; __builtin_memcpy(&u, &v, 4); return u;
#else
  return (unsigned)f2bf(lo) | ((unsigned)f2bf(hi) << 16);
#endif
}

// W transposed+swizzled in LDS: element (n,k) at n*128 + (((k>>3)^(n&15))<<3) + (k&7)
// -> B-frag ds_read_b128 conflict-free.
__device__ __forceinline__ void stageW(const float* __restrict__ W,
                                       unsigned short* __restrict__ sW, int tid) {
  const int n = tid & 127;
  const int tg = tid >> 7;
  #pragma unroll
  for (int iter = 0; iter < 16; ++iter) {
    const int k0 = iter * 8 + tg * 4;
    float w0 = W[(k0 + 0) * D + n];
    float w1 = W[(k0 + 1) * D + n];
    float w2 = W[(k0 + 2) * D + n];
    float w3 = W[(k0 + 3) * D + n];
    uint2 pp = make_uint2(pkbf(w0, w1), pkbf(w2, w3));
    const int idx = n * D + (((k0 >> 3) ^ (n & 15)) << 3) + (k0 & 7);
    *(uint2*)&sW[idx] = pp;   // 8B-aligned: (k0&7) in {0,4}
  }
}

__device__ __forceinline__ short8 cvt_a(const floatx4& f0, const floatx4& f1) {
  uintx4 u;
  u[0] = pkbf(f0[0], f0[1]);
  u[1] = pkbf(f0[2], f0[3]);
  u[2] = pkbf(f1[0], f1[1]);
  u[3] = pkbf(f1[2], f1[3]);
  short8 a; __builtin_memcpy(&a, &u, 16); return a;
}

// bias+relu+pack epilogue into the per-wave swizzled sH buffer.
__device__ __forceinline__ void epilogue(const floatx4 acc[8], const float bias[8],
                                         unsigned short* __restrict__ mysH,
                                         int quad, int l16) {
  #pragma unroll
  for (int n0 = 0; n0 < 8; ++n0) {
    const int g = 2 * n0 + (l16 >> 3);
    float v0 = fmaxf(acc[n0][0] + bias[n0], 0.f);
    float v1 = fmaxf(acc[n0][1] + bias[n0], 0.f);
    float v2 = fmaxf(acc[n0][2] + bias[n0], 0.f);
    float v3 = fmaxf(acc[n0][3] + bias[n0], 0.f);
    unsigned p01 = pkbf(v0, v1);
    unsigned p23 = pkbf(v2, v3);
    const int r0 = quad * 4;
    mysH[(r0 + 0) * D + (((g ^ (r0 + 0)) & 15) << 3) + (l16 & 7)] = (unsigned short)(p01 & 0xFFFFu);
    mysH[(r0 + 1) * D + (((g ^ (r0 + 1)) & 15) << 3) + (l16 & 7)] = (unsigned short)(p01 >> 16);
    mysH[(r0 + 2) * D + (((g ^ (r0 + 2)) & 15) << 3) + (l16 & 7)] = (unsigned short)(p23 & 0xFFFFu);
    mysH[(r0 + 3) * D + (((g ^ (r0 + 3)) & 15) << 3) + (l16 & 7)] = (unsigned short)(p23 >> 16);
  }
}

// Fused 2-layer MLP, register-blocked 2x (32 rows/wave/iter); h1 lives in a
// per-wave XOR-swizzled 16x128 LDS buffer reused sequentially by both halves.
__global__ __launch_bounds__(256) void mlp_fused(
    const float* __restrict__ x, const float* __restrict__ W1,
    const float* __restrict__ b1, const float* __restrict__ W2,
    const float* __restrict__ b2, unsigned short* __restrict__ h,
    const int* __restrict__ elabel, float* __restrict__ out,
    int nNodes, int npairs, int E) {
  __shared__ unsigned short sW1[D * D];          // 32 KB
  __shared__ unsigned short sW2[D * D];          // 32 KB
  __shared__ unsigned short sH[NWAVES][16 * D];  // 16 KB
  const int tid = threadIdx.x;
  const int wave = tid >> 6, lane = tid & 63;
  const int quad = lane >> 4, l16 = lane & 15;

  // labels: vectorized int4 -> float4, overlapped with W staging
  {
    const int E4 = E & ~3;
    for (int li = (blockIdx.x * 256 + tid) * 4; li < E4; li += GRID_MLP * 256 * 4) {
      int4 lv = *(const int4*)&elabel[li];
      float4 fv = make_float4((float)lv.x, (float)lv.y, (float)lv.z, (float)lv.w);
      *(float4*)&out[E + li] = fv;
    }
    if (blockIdx.x == 0 && tid < (E & 3)) out[E + E4 + tid] = (float)elabel[E4 + tid];
  }

  stageW(W1, sW1, tid);
  stageW(W2, sW2, tid);
  __syncthreads();

  float bias1[8], bias2[8];
  #pragma unroll
  for (int n0 = 0; n0 < 8; ++n0) { bias1[n0] = b1[n0 * 16 + l16]; bias2[n0] = b2[n0 * 16 + l16]; }

  unsigned short* mysH = sH[wave];

  for (int p = blockIdx.x * NWAVES + wave; p < npairs; p += GRID_MLP * NWAVES) {
    const int mbase = p * 32;
    const int m0 = mbase + l16;
    const int m1 = m0 + 16;
    floatx4 xf0[8], xf1[8];
    {
      const floatx4* xp0 = (const floatx4*)(x + (size_t)m0 * D + quad * 8);
      const floatx4* xp1 = (const floatx4*)(x + (size_t)m1 * D + quad * 8);
      const bool v0 = (m0 < nNodes), v1 = (m1 < nNodes);
      #pragma unroll
      for (int i = 0; i < 8; ++i) {
        const int o = (i >> 1) * 8 + (i & 1);
        xf0[i] = v0 ? xp0[o] : (floatx4){0.f, 0.f, 0.f, 0.f};
        xf1[i] = v1 ? xp1[o] : (floatx4){0.f, 0.f, 0.f, 0.f};
      }
    }
    // ---- layer 1 ----
    floatx4 acc0[8], acc1[8];
    #pragma unroll
    for (int n0 = 0; n0 < 8; ++n0) {
      acc0[n0] = (floatx4){0.f, 0.f, 0.f, 0.f};
      acc1[n0] = (floatx4){0.f, 0.f, 0.f, 0.f};
    }
    #pragma unroll
    for (int kk = 0; kk < 4; ++kk) {
      const short8 a0 = cvt_a(xf0[2 * kk], xf0[2 * kk + 1]);
      const short8 a1 = cvt_a(xf1[2 * kk], xf1[2 * kk + 1]);
      #pragma unroll
      for (int n0 = 0; n0 < 8; ++n0) {
        short8 b = *(const short8*)&sW1[(n0 * 16 + l16) * D + (((kk * 4 + quad) ^ l16) << 3)];
        acc0[n0] = __builtin_amdgcn_mfma_f32_16x16x32_bf16(a0, b, acc0[n0], 0, 0, 0);
        acc1[n0] = __builtin_amdgcn_mfma_f32_16x16x32_bf16(a1, b, acc1[n0], 0, 0, 0);
      }
    }
    // epilogue 1 half 0 -> sH, read A-frags; then half 1
    short8 af0[4], af1[4];
    epilogue(acc0, bias1, mysH, quad, l16);
    #pragma unroll
    for (int kk = 0; kk < 4; ++kk)
      af0[kk] = *(const short8*)&mysH[l16 * D + ((((kk * 4 + quad) ^ l16) & 15) << 3)];
    epilogue(acc1, bias1, mysH, quad, l16);
    #pragma unroll
    for (int kk = 0; kk < 4; ++kk)
      af1[kk] = *(const short8*)&mysH[l16 * D + ((((kk * 4 + quad) ^ l16) & 15) << 3)];
    // ---- layer 2 ----
    #pragma unroll
    for (int n0 = 0; n0 < 8; ++n0) {
      acc0[n0] = (floatx4){0.f, 0.f, 0.f, 0.f};
      acc1[n0] = (floatx4){0.f, 0.f, 0.f, 0.f};
    }
    #pragma unroll
    for (int kk = 0; kk < 4; ++kk) {
      #pragma unroll
      for (int n0 = 0; n0 < 8; ++n0) {
        short8 b = *(const short8*)&sW2[(n0 * 16 + l16) * D + (((kk * 4 + quad) ^ l16) << 3)];
        acc0[n0] = __builtin_amdgcn_mfma_f32_16x16x32_bf16(af0[kk], b, acc0[n0], 0, 0, 0);
        acc1[n0] = __builtin_amdgcn_mfma_f32_16x16x32_bf16(af1[kk], b, acc1[n0], 0, 0, 0);
      }
    }
    // epilogue 2 + store, half 0
    epilogue(acc0, bias2, mysH, quad, l16);
    #pragma unroll
    for (int i = 0; i < 4; ++i) {
      const int row = i * 4 + quad;
      short8 vrow = *(const short8*)&mysH[row * D + (((l16 ^ row) & 15) << 3)];
      const int g = mbase + row;
      if (g < nNodes) *(short8*)&h[(size_t)g * D + l16 * 8] = vrow;
    }
    // epilogue 2 + store, half 1
    epilogue(acc1, bias2, mysH, quad, l16);
    #pragma unroll
    for (int i = 0; i < 4; ++i) {
      const int row = i * 4 + quad;
      short8 vrow = *(const short8*)&mysH[row * D + (((l16 ^ row) & 15) << 3)];
      const int g = mbase + 16 + row;
      if (g < nNodes) *(short8*)&h[(size_t)g * D + l16 * 8] = vrow;
    }
  }
}

__device__ __forceinline__ float dot2bf(unsigned a, unsigned b, float acc) {
  float a0 = __uint_as_float(a << 16);
  float a1 = __uint_as_float(a & 0xFFFF0000u);
  float b0 = __uint_as_float(b << 16);
  float b1 = __uint_as_float(b & 0xFFFF0000u);
  acc = fmaf(a0, b0, acc);
  acc = fmaf(a1, b1, acc);
  return acc;
}

__device__ __forceinline__ float edge_dot(const uint4& a, const uint4& b) {
  float acc = 0.f;
  acc = dot2bf(a.x, b.x, acc);
  acc = dot2bf(a.y, b.y, acc);
  acc = dot2bf(a.z, b.z, acc);
  acc = dot2bf(a.w, b.w, acc);
  acc += __shfl_xor(acc, 8);
  acc += __shfl_xor(acc, 4);
  acc += __shfl_xor(acc, 2);
  acc += __shfl_xor(acc, 1);
  return acc;
}

// Edge decode: 16 lanes/edge, 8 edges per group -> 16 gathers (256B) in flight.
// One-shot blocks (3907): block churn keeps the load pipe full.
__global__ __launch_bounds__(256) void edge_kernel(
    const unsigned short* __restrict__ h2, const int* __restrict__ eidx,
    float* __restrict__ out, int E) {
  const int sub = threadIdx.x & 15;
  const int grp = (blockIdx.x * 256 + threadIdx.x) >> 4;
  const int e0 = grp * 8;
  if (e0 + 8 <= E) {
    const int4 s0 = *(const int4*)&eidx[e0];
    const int4 s1 = *(const int4*)&eidx[e0 + 4];
    const int4 t0 = *(const int4*)&eidx[E + e0];
    const int4 t1 = *(const int4*)&eidx[E + e0 + 4];
    int s[8] = {s0.x, s0.y, s0.z, s0.w, s1.x, s1.y, s1.z, s1.w};
    int d[8] = {t0.x, t0.y, t0.z, t0.w, t1.x, t1.y, t1.z, t1.w};
    uint4 va[8], vb[8];
    #pragma unroll
    for (int i = 0; i < 8; ++i) {
      va[i] = *(const uint4*)(h2 + (((size_t)(unsigned)s[i]) << 7) + sub * 8);
      vb[i] = *(const uint4*)(h2 + (((size_t)(unsigned)d[i]) << 7) + sub * 8);
    }
    #pragma unroll
    for (int i = 0; i < 8; ++i) {
      float acc = edge_dot(va[i], vb[i]);
      if (sub == 0) out[e0 + i] = acc;
    }
  } else if (e0 < E) {
    for (int e = e0; e < E; ++e) {
      const int s = eidx[e];
      const int d = eidx[E + e];
      const uint4 ua = *(const uint4*)(h2 + (((size_t)(unsigned)s) << 7) + sub * 8);
      const uint4 ub = *(const uint4*)(h2 + (((size_t)(unsigned)d) << 7) + sub * 8);
      float acc = edge_dot(ua, ub);
      if (sub == 0) out[e] = acc;
    }
  }
}

extern "C" void kernel_launch(void* const* d_in, const int* in_sizes, int n_in,
                              void* d_out, int out_size, void* d_ws, size_t ws_size,
                              hipStream_t stream) {
  const float* x  = (const float*)d_in[0];
  const int* eidx = (const int*)d_in[1];
  const int* elab = (const int*)d_in[2];
  const float* W1 = (const float*)d_in[3];
  const float* b1 = (const float*)d_in[4];
  const float* W2 = (const float*)d_in[5];
  const float* b2 = (const float*)d_in[6];
  float* out = (float*)d_out;

  const int nNodes = in_sizes[0] / D;   // 100000
  const int E = in_sizes[2];            // 500000
  const int npairs = (nNodes + 31) / 32;

  unsigned short* h = (unsigned short*)d_ws;  // nNodes*128 bf16 = 25.6 MB

  mlp_fused<<<GRID_MLP, 256, 0, stream>>>(x, W1, b1, W2, b2, h, elab, out,
                                          nNodes, npairs, E);

  const int edgeBlocks = (E + 127) / 128;   // 8 edges per 16-lane group
  edge_kernel<<<edgeBlocks, 256, 0, stream>>>(h, eidx, out, E);
}

// Round 9
// 140.642 us; speedup vs baseline: 1.0048x; 1.0048x over previous
//
#include <hip/hip_runtime.h>

typedef __attribute__((ext_vector_type(8))) short short8;
typedef __attribute__((ext_vector_type(4))) short short4v;
typedef __attribute__((ext_vector_type(4))) float floatx4;
typedef __attribute__((ext_vector_type(4))) unsigned uintx4;

#define D 128
#define NWAVES 4
#define GRID_MLP 512

__device__ __forceinline__ unsigned short f2bf(float f) {
  unsigned u = __float_as_uint(f);
  u += 0x7FFFu + ((u >> 16) & 1u);   // RNE
  return (unsigned short)(u >> 16);
}

// Packed f32x2 -> bf16x2 (RNE) via v_cvt_pk_bf16_f32 where available.
__device__ __forceinline__ unsigned pkbf(float lo, float hi) {
#if __has_builtin(__builtin_amdgcn_cvt_pk_bf16_f32)
  auto v = __builtin_amdgcn_cvt_pk_bf16_f32(lo, hi);
  unsigned u; __builtin_memcpy(&u, &v, 4); return u;
#else
  return (unsigned)f2bf(lo) | ((unsigned)f2bf(hi) << 16);
#endif
}

// W transposed+swizzled in LDS: element (n,k) at n*128 + (((k>>3)^(n&15))<<3) + (k&7)
// -> B-frag ds_read_b128 conflict-free.
__device__ __forceinline__ void stageW(const float* __restrict__ W,
                                       unsigned short* __restrict__ sW, int tid) {
  const int n = tid & 127;
  const int tg = tid >> 7;
  #pragma unroll
  for (int iter = 0; iter < 16; ++iter) {
    const int k0 = iter * 8 + tg * 4;
    float w0 = W[(k0 + 0) * D + n];
    float w1 = W[(k0 + 1) * D + n];
    float w2 = W[(k0 + 2) * D + n];
    float w3 = W[(k0 + 3) * D + n];
    uint2 pp = make_uint2(pkbf(w0, w1), pkbf(w2, w3));
    const int idx = n * D + (((k0 >> 3) ^ (n & 15)) << 3) + (k0 & 7);
    *(uint2*)&sW[idx] = pp;   // 8B-aligned: (k0&7) in {0,4}
  }
}

__device__ __forceinline__ short8 cvt_a(const floatx4& f0, const floatx4& f1) {
  uintx4 u;
  u[0] = pkbf(f0[0], f0[1]);
  u[1] = pkbf(f0[2], f0[3]);
  u[2] = pkbf(f1[0], f1[1]);
  u[3] = pkbf(f1[2], f1[3]);
  short8 a; __builtin_memcpy(&a, &u, 16); return a;
}

// bias+relu+pack epilogue into the per-wave swizzled sH buffer.
__device__ __forceinline__ void epilogue(const floatx4 acc[8], const float bias[8],
                                         unsigned short* __restrict__ mysH,
                                         int quad, int l16) {
  #pragma unroll
  for (int n0 = 0; n0 < 8; ++n0) {
    const int g = 2 * n0 + (l16 >> 3);
    float v0 = fmaxf(acc[n0][0] + bias[n0], 0.f);
    float v1 = fmaxf(acc[n0][1] + bias[n0], 0.f);
    float v2 = fmaxf(acc[n0][2] + bias[n0], 0.f);
    float v3 = fmaxf(acc[n0][3] + bias[n0], 0.f);
    unsigned p01 = pkbf(v0, v1);
    unsigned p23 = pkbf(v2, v3);
    const int r0 = quad * 4;
    mysH[(r0 + 0) * D + (((g ^ (r0 + 0)) & 15) << 3) + (l16 & 7)] = (unsigned short)(p01 & 0xFFFFu);
    mysH[(r0 + 1) * D + (((g ^ (r0 + 1)) & 15) << 3) + (l16 & 7)] = (unsigned short)(p01 >> 16);
    mysH[(r0 + 2) * D + (((g ^ (r0 + 2)) & 15) << 3) + (l16 & 7)] = (unsigned short)(p23 & 0xFFFFu);
    mysH[(r0 + 3) * D + (((g ^ (r0 + 3)) & 15) << 3) + (l16 & 7)] = (unsigned short)(p23 >> 16);
  }
}

// Fused 2-layer MLP, register-blocked 2x (32 rows/wave/iter); h1 lives in a
// per-wave XOR-swizzled 16x128 LDS buffer reused sequentially by both halves.
__global__ __launch_bounds__(256) void mlp_fused(
    const float* __restrict__ x, const float* __restrict__ W1,
    const float* __restrict__ b1, const float* __restrict__ W2,
    const float* __restrict__ b2, unsigned short* __restrict__ h,
    const int* __restrict__ elabel, float* __restrict__ out,
    int nNodes, int npairs, int E) {
  __shared__ unsigned short sW1[D * D];          // 32 KB
  __shared__ unsigned short sW2[D * D];          // 32 KB
  __shared__ unsigned short sH[NWAVES][16 * D];  // 16 KB
  const int tid = threadIdx.x;
  const int wave = tid >> 6, lane = tid & 63;
  const int quad = lane >> 4, l16 = lane & 15;

  // labels: vectorized int4 -> float4, overlapped with W staging
  {
    const int E4 = E & ~3;
    for (int li = (blockIdx.x * 256 + tid) * 4; li < E4; li += GRID_MLP * 256 * 4) {
      int4 lv = *(const int4*)&elabel[li];
      float4 fv = make_float4((float)lv.x, (float)lv.y, (float)lv.z, (float)lv.w);
      *(float4*)&out[E + li] = fv;
    }
    if (blockIdx.x == 0 && tid < (E & 3)) out[E + E4 + tid] = (float)elabel[E4 + tid];
  }

  stageW(W1, sW1, tid);
  stageW(W2, sW2, tid);
  __syncthreads();

  float bias1[8], bias2[8];
  #pragma unroll
  for (int n0 = 0; n0 < 8; ++n0) { bias1[n0] = b1[n0 * 16 + l16]; bias2[n0] = b2[n0 * 16 + l16]; }

  unsigned short* mysH = sH[wave];

  for (int p = blockIdx.x * NWAVES + wave; p < npairs; p += GRID_MLP * NWAVES) {
    const int mbase = p * 32;
    const int m0 = mbase + l16;
    const int m1 = m0 + 16;
    floatx4 xf0[8], xf1[8];
    {
      const floatx4* xp0 = (const floatx4*)(x + (size_t)m0 * D + quad * 8);
      const floatx4* xp1 = (const floatx4*)(x + (size_t)m1 * D + quad * 8);
      const bool v0 = (m0 < nNodes), v1 = (m1 < nNodes);
      #pragma unroll
      for (int i = 0; i < 8; ++i) {
        const int o = (i >> 1) * 8 + (i & 1);
        xf0[i] = v0 ? xp0[o] : (floatx4){0.f, 0.f, 0.f, 0.f};
        xf1[i] = v1 ? xp1[o] : (floatx4){0.f, 0.f, 0.f, 0.f};
      }
    }
    // ---- layer 1 ----
    floatx4 acc0[8], acc1[8];
    #pragma unroll
    for (int n0 = 0; n0 < 8; ++n0) {
      acc0[n0] = (floatx4){0.f, 0.f, 0.f, 0.f};
      acc1[n0] = (floatx4){0.f, 0.f, 0.f, 0.f};
    }
    #pragma unroll
    for (int kk = 0; kk < 4; ++kk) {
      const short8 a0 = cvt_a(xf0[2 * kk], xf0[2 * kk + 1]);
      const short8 a1 = cvt_a(xf1[2 * kk], xf1[2 * kk + 1]);
      #pragma unroll
      for (int n0 = 0; n0 < 8; ++n0) {
        short8 b = *(const short8*)&sW1[(n0 * 16 + l16) * D + (((kk * 4 + quad) ^ l16) << 3)];
        acc0[n0] = __builtin_amdgcn_mfma_f32_16x16x32_bf16(a0, b, acc0[n0], 0, 0, 0);
        acc1[n0] = __builtin_amdgcn_mfma_f32_16x16x32_bf16(a1, b, acc1[n0], 0, 0, 0);
      }
    }
    // epilogue 1 half 0 -> sH, read A-frags; then half 1
    short8 af0[4], af1[4];
    epilogue(acc0, bias1, mysH, quad, l16);
    #pragma unroll
    for (int kk = 0; kk < 4; ++kk)
      af0[kk] = *(const short8*)&mysH[l16 * D + ((((kk * 4 + quad) ^ l16) & 15) << 3)];
    epilogue(acc1, bias1, mysH, quad, l16);
    #pragma unroll
    for (int kk = 0; kk < 4; ++kk)
      af1[kk] = *(const short8*)&mysH[l16 * D + ((((kk * 4 + quad) ^ l16) & 15) << 3)];
    // ---- layer 2 ----
    #pragma unroll
    for (int n0 = 0; n0 < 8; ++n0) {
      acc0[n0] = (floatx4){0.f, 0.f, 0.f, 0.f};
      acc1[n0] = (floatx4){0.f, 0.f, 0.f, 0.f};
    }
    #pragma unroll
    for (int kk = 0; kk < 4; ++kk) {
      #pragma unroll
      for (int n0 = 0; n0 < 8; ++n0) {
        short8 b = *(const short8*)&sW2[(n0 * 16 + l16) * D + (((kk * 4 + quad) ^ l16) << 3)];
        acc0[n0] = __builtin_amdgcn_mfma_f32_16x16x32_bf16(af0[kk], b, acc0[n0], 0, 0, 0);
        acc1[n0] = __builtin_amdgcn_mfma_f32_16x16x32_bf16(af1[kk], b, acc1[n0], 0, 0, 0);
      }
    }
    // epilogue 2 + store, half 0
    epilogue(acc0, bias2, mysH, quad, l16);
    #pragma unroll
    for (int i = 0; i < 4; ++i) {
      const int row = i * 4 + quad;
      short8 vrow = *(const short8*)&mysH[row * D + (((l16 ^ row) & 15) << 3)];
      const int g = mbase + row;
      if (g < nNodes) *(short8*)&h[(size_t)g * D + l16 * 8] = vrow;
    }
    // epilogue 2 + store, half 1
    epilogue(acc1, bias2, mysH, quad, l16);
    #pragma unroll
    for (int i = 0; i < 4; ++i) {
      const int row = i * 4 + quad;
      short8 vrow = *(const short8*)&mysH[row * D + (((l16 ^ row) & 15) << 3)];
      const int g = mbase + 16 + row;
      if (g < nNodes) *(short8*)&h[(size_t)g * D + l16 * 8] = vrow;
    }
  }
}

__device__ __forceinline__ float dot2bf(unsigned a, unsigned b, float acc) {
  float a0 = __uint_as_float(a << 16);
  float a1 = __uint_as_float(a & 0xFFFF0000u);
  float b0 = __uint_as_float(b << 16);
  float b1 = __uint_as_float(b & 0xFFFF0000u);
  acc = fmaf(a0, b0, acc);
  acc = fmaf(a1, b1, acc);
  return acc;
}

__device__ __forceinline__ float dot_u4(const uint4& a, const uint4& b, float acc) {
  acc = dot2bf(a.x, b.x, acc);
  acc = dot2bf(a.y, b.y, acc);
  acc = dot2bf(a.z, b.z, acc);
  acc = dot2bf(a.w, b.w, acc);
  return acc;
}

// Edge decode: 8 lanes/edge (each lane 32B of the row via two uint4 loads),
// 8 edges per group -> 32 gathers (512B) in flight per thread.
// One-shot blocks: block churn keeps the load pipe full.
__global__ __launch_bounds__(256) void edge_kernel(
    const unsigned short* __restrict__ h2, const int* __restrict__ eidx,
    float* __restrict__ out, int E) {
  const int sub = threadIdx.x & 7;                       // lane within group
  const int grp = (blockIdx.x * 256 + threadIdx.x) >> 3; // global 8-edge group
  const int e0 = grp * 8;
  const size_t off = (size_t)(sub * 16);                 // 16 shorts = 32 B
  if (e0 + 8 <= E) {
    const int4 s0 = *(const int4*)&eidx[e0];
    const int4 s1 = *(const int4*)&eidx[e0 + 4];
    const int4 t0 = *(const int4*)&eidx[E + e0];
    const int4 t1 = *(const int4*)&eidx[E + e0 + 4];
    int s[8] = {s0.x, s0.y, s0.z, s0.w, s1.x, s1.y, s1.z, s1.w};
    int d[8] = {t0.x, t0.y, t0.z, t0.w, t1.x, t1.y, t1.z, t1.w};
    uint4 va[8][2], vb[8][2];
    #pragma unroll
    for (int i = 0; i < 8; ++i) {
      const unsigned short* ps = h2 + (((size_t)(unsigned)s[i]) << 7) + off;
      const unsigned short* pd = h2 + (((size_t)(unsigned)d[i]) << 7) + off;
      va[i][0] = *(const uint4*)(ps);
      va[i][1] = *(const uint4*)(ps + 8);
      vb[i][0] = *(const uint4*)(pd);
      vb[i][1] = *(const uint4*)(pd + 8);
    }
    #pragma unroll
    for (int i = 0; i < 8; ++i) {
      float acc = 0.f;
      acc = dot_u4(va[i][0], vb[i][0], acc);
      acc = dot_u4(va[i][1], vb[i][1], acc);
      acc += __shfl_xor(acc, 4);
      acc += __shfl_xor(acc, 2);
      acc += __shfl_xor(acc, 1);
      if (sub == 0) out[e0 + i] = acc;
    }
  } else if (e0 < E) {
    for (int e = e0; e < E; ++e) {
      const unsigned short* ps = h2 + (((size_t)(unsigned)eidx[e]) << 7) + off;
      const unsigned short* pd = h2 + (((size_t)(unsigned)eidx[E + e]) << 7) + off;
      float acc = 0.f;
      acc = dot_u4(*(const uint4*)(ps), *(const uint4*)(pd), acc);
      acc = dot_u4(*(const uint4*)(ps + 8), *(const uint4*)(pd + 8), acc);
      acc += __shfl_xor(acc, 4);
      acc += __shfl_xor(acc, 2);
      acc += __shfl_xor(acc, 1);
      if (sub == 0) out[e] = acc;
    }
  }
}

extern "C" void kernel_launch(void* const* d_in, const int* in_sizes, int n_in,
                              void* d_out, int out_size, void* d_ws, size_t ws_size,
                              hipStream_t stream) {
  const float* x  = (const float*)d_in[0];
  const int* eidx = (const int*)d_in[1];
  const int* elab = (const int*)d_in[2];
  const float* W1 = (const float*)d_in[3];
  const float* b1 = (const float*)d_in[4];
  const float* W2 = (const float*)d_in[5];
  const float* b2 = (const float*)d_in[6];
  float* out = (float*)d_out;

  const int nNodes = in_sizes[0] / D;   // 100000
  const int E = in_sizes[2];            // 500000
  const int npairs = (nNodes + 31) / 32;

  unsigned short* h = (unsigned short*)d_ws;  // nNodes*128 bf16 = 25.6 MB

  mlp_fused<<<GRID_MLP, 256, 0, stream>>>(x, W1, b1, W2, b2, h, elab, out,
                                          nNodes, npairs, E);

  // 8 edges per 8-lane group -> 32 groups (256 edges) per block
  const int edgeBlocks = (E + 255) / 256;
  edge_kernel<<<edgeBlocks, 256, 0, stream>>>(h, eidx, out, E);
}